// Round 1
// baseline (549.974 us; speedup 1.0000x reference)
//
#include <hip/hip_runtime.h>
#include <math.h>

#define SEQ 4096
#define DM  1024
#define DFF 4096
#define NH  2
#define HD  512

typedef unsigned short ushort_t;
typedef short  s16x8 __attribute__((ext_vector_type(8)));
typedef float  f32x4 __attribute__((ext_vector_type(4)));
typedef unsigned short u16x8 __attribute__((ext_vector_type(8)));

__device__ __forceinline__ float bf2f(unsigned short u) {
    return __uint_as_float(((unsigned)u) << 16);
}
__device__ __forceinline__ unsigned short f2bf(float f) {
    unsigned u = __float_as_uint(f);
    unsigned r = (u + 0x7fffu + ((u >> 16) & 1u)) >> 16;
    return (unsigned short)r;
}

__device__ __forceinline__ void async_load16(void* lds, const void* g) {
    __builtin_amdgcn_global_load_lds(
        (const __attribute__((address_space(1))) void*)g,
        (__attribute__((address_space(3))) void*)lds, 16, 0, 0);
}

// ---------------------------------------------------------------------------
// NT GEMM: C[M,N] = alpha * A[M,K] * B[N,K]^T (+bias[n]) (gelu) (+res[m,n])
// A,B bf16 (ushort bits), C bf16 or fp32. 128x128 block tile, 256 threads
// (4 waves, each 64x64 via 4x4 of 16x16x32 MFMA). BK=64, global_load_lds x16.
// blockIdx.z batches over {A,B,C,bias} strides.
// ---------------------------------------------------------------------------
template<bool HAS_BIAS, bool DO_GELU, bool HAS_RES, bool OUT_BF16>
__global__ __launch_bounds__(256)
void gemm_nt(const ushort_t* __restrict__ A, int lda,
             const ushort_t* __restrict__ B, int ldb,
             void* __restrict__ Cv, int ldc,
             const float* __restrict__ bias,
             const float* __restrict__ res, int ldres,
             int K, float alpha,
             size_t strA, size_t strB, size_t strC, size_t strBias)
{
    __shared__ alignas(16) ushort_t sA[128 * 64];
    __shared__ alignas(16) ushort_t sB[128 * 64];

    const int z = blockIdx.z;
    A += (size_t)z * strA;
    B += (size_t)z * strB;
    if (HAS_BIAS) bias += (size_t)z * strBias;

    const int tid   = threadIdx.x;
    const int lane  = tid & 63;
    const int wave  = tid >> 6;
    const int waveM = wave >> 1, waveN = wave & 1;
    const int m0 = blockIdx.y * 128, n0 = blockIdx.x * 128;
    const int lr = lane & 15, quad = lane >> 4;

    f32x4 acc[4][4] = {};

    const ushort_t* Ag = A + (size_t)m0 * lda;
    const ushort_t* Bg = B + (size_t)n0 * ldb;

    const int ldRow = (lane >> 3);        // 0..7
    const int ldCol = (lane & 7) * 8;     // element col offset

    for (int k0 = 0; k0 < K; k0 += 64) {
#pragma unroll
        for (int i = 0; i < 4; ++i) {
            int r = wave * 32 + i * 8 + ldRow;
            async_load16(&sA[(wave * 32 + i * 8) * 64],
                         Ag + (size_t)r * lda + k0 + ldCol);
            async_load16(&sB[(wave * 32 + i * 8) * 64],
                         Bg + (size_t)r * ldb + k0 + ldCol);
        }
        __syncthreads();   // drains vmcnt before barrier -> LDS data visible

#pragma unroll
        for (int kk = 0; kk < 64; kk += 32) {
            s16x8 af[4], bfr[4];
#pragma unroll
            for (int mi = 0; mi < 4; ++mi)
                af[mi] = *(const s16x8*)&sA[(waveM * 64 + mi * 16 + lr) * 64 + kk + quad * 8];
#pragma unroll
            for (int ni = 0; ni < 4; ++ni)
                bfr[ni] = *(const s16x8*)&sB[(waveN * 64 + ni * 16 + lr) * 64 + kk + quad * 8];
#pragma unroll
            for (int mi = 0; mi < 4; ++mi)
#pragma unroll
                for (int ni = 0; ni < 4; ++ni)
                    acc[mi][ni] = __builtin_amdgcn_mfma_f32_16x16x32_bf16(
                        af[mi], bfr[ni], acc[mi][ni], 0, 0, 0);
        }
        __syncthreads();   // WAR: next stage overwrites LDS
    }

    // Epilogue. C/D layout: col = lane&15, row = quad*4 + reg (m89-verified).
#pragma unroll
    for (int mi = 0; mi < 4; ++mi) {
#pragma unroll
        for (int ni = 0; ni < 4; ++ni) {
            int row = m0 + waveM * 64 + mi * 16 + quad * 4;
            int col = n0 + waveN * 64 + ni * 16 + lr;
            float bval = HAS_BIAS ? bias[col] : 0.0f;
#pragma unroll
            for (int r = 0; r < 4; ++r) {
                float v = acc[mi][ni][r] * alpha + bval;
                if (DO_GELU) {
                    float xx = v;
                    float inner = 0.7978845608028654f * (xx + 0.044715f * xx * xx * xx);
                    v = 0.5f * xx * (1.0f + tanhf(inner));
                }
                if (HAS_RES) v += res[(size_t)(row + r) * ldres + col];
                if (OUT_BF16)
                    ((ushort_t*)Cv)[(size_t)z * strC + (size_t)(row + r) * ldc + col] = f2bf(v);
                else
                    ((float*)Cv)[(size_t)z * strC + (size_t)(row + r) * ldc + col] = v;
            }
        }
    }
}

// ---------------------------------------------------------------------------
// LayerNorm: one block per row of 1024 fp32; out bf16.
// ---------------------------------------------------------------------------
__global__ __launch_bounds__(256)
void layernorm_kernel(const float* __restrict__ x, const float* __restrict__ g,
                      const float* __restrict__ b, ushort_t* __restrict__ out)
{
    int row = blockIdx.x;
    int tid = threadIdx.x;
    float4 v = ((const float4*)(x + (size_t)row * DM))[tid];
    float s1 = v.x + v.y + v.z + v.w;
    float s2 = v.x * v.x + v.y * v.y + v.z * v.z + v.w * v.w;
#pragma unroll
    for (int o = 32; o > 0; o >>= 1) {
        s1 += __shfl_down(s1, o);
        s2 += __shfl_down(s2, o);
    }
    __shared__ float r1[4], r2[4];
    if ((tid & 63) == 0) { r1[tid >> 6] = s1; r2[tid >> 6] = s2; }
    __syncthreads();
    s1 = r1[0] + r1[1] + r1[2] + r1[3];
    s2 = r2[0] + r2[1] + r2[2] + r2[3];
    float mu  = s1 * (1.0f / DM);
    float var = s2 * (1.0f / DM) - mu * mu;
    float rs  = rsqrtf(var + 1e-5f);
    float4 gg = ((const float4*)g)[tid];
    float4 bb = ((const float4*)b)[tid];
    ushort_t* o = out + (size_t)row * DM + tid * 4;
    o[0] = f2bf((v.x - mu) * rs * gg.x + bb.x);
    o[1] = f2bf((v.y - mu) * rs * gg.y + bb.y);
    o[2] = f2bf((v.z - mu) * rs * gg.z + bb.z);
    o[3] = f2bf((v.w - mu) * rs * gg.w + bb.w);
}

// ---------------------------------------------------------------------------
// Row softmax in-place on bf16 scores [rows x 4096]. One block per row.
// Each thread owns 2 contiguous 8-elem chunks (fully coalesced 16B accesses).
// ---------------------------------------------------------------------------
__global__ __launch_bounds__(256)
void softmax_kernel(ushort_t* __restrict__ S)
{
    size_t row = blockIdx.x;
    ushort_t* p = S + row * (size_t)SEQ;
    int tid = threadIdx.x;
    u16x8 ra = *(const u16x8*)(p + tid * 8);
    u16x8 rb = *(const u16x8*)(p + 2048 + tid * 8);
    float v[16];
    float vmax = -1e30f;
#pragma unroll
    for (int i = 0; i < 8; ++i) {
        v[i]     = bf2f(ra[i]);
        v[8 + i] = bf2f(rb[i]);
    }
#pragma unroll
    for (int i = 0; i < 16; ++i) vmax = fmaxf(vmax, v[i]);
#pragma unroll
    for (int o = 32; o > 0; o >>= 1) vmax = fmaxf(vmax, __shfl_down(vmax, o));
    __shared__ float sred[8];
    if ((tid & 63) == 0) sred[tid >> 6] = vmax;
    __syncthreads();
    vmax = fmaxf(fmaxf(sred[0], sred[1]), fmaxf(sred[2], sred[3]));
    float s = 0.0f;
#pragma unroll
    for (int i = 0; i < 16; ++i) { v[i] = __expf(v[i] - vmax); s += v[i]; }
#pragma unroll
    for (int o = 32; o > 0; o >>= 1) s += __shfl_down(s, o);
    if ((tid & 63) == 0) sred[4 + (tid >> 6)] = s;
    __syncthreads();
    s = sred[4] + sred[5] + sred[6] + sred[7];
    float inv = 1.0f / s;
    u16x8 oa, ob;
#pragma unroll
    for (int i = 0; i < 8; ++i) {
        oa[i] = f2bf(v[i] * inv);
        ob[i] = f2bf(v[8 + i] * inv);
    }
    *(u16x8*)(p + tid * 8) = oa;
    *(u16x8*)(p + 2048 + tid * 8) = ob;
}

// ---------------------------------------------------------------------------
// fp32 -> bf16 cast (vectorized)
// ---------------------------------------------------------------------------
__global__ __launch_bounds__(256)
void cast_f32_bf16(const float4* __restrict__ src, ushort_t* __restrict__ dst, int n4)
{
    int i = blockIdx.x * blockDim.x + threadIdx.x;
    if (i < n4) {
        float4 f = src[i];
        ushort_t* d = dst + (size_t)i * 4;
        d[0] = f2bf(f.x); d[1] = f2bf(f.y); d[2] = f2bf(f.z); d[3] = f2bf(f.w);
    }
}

// ---------------------------------------------------------------------------
// Per-head transpose: Vt[h][d][t] = V[t][h*HD + d]  (bf16)
// 64x64 tiles via LDS.
// ---------------------------------------------------------------------------
__global__ __launch_bounds__(256)
void transpose_head(const ushort_t* __restrict__ V, ushort_t* __restrict__ Vt)
{
    __shared__ ushort_t tile[64][65];
    int t0 = blockIdx.x * 64, d0 = blockIdx.y * 64, h = blockIdx.z;
    int tid = threadIdx.x;
    for (int i = tid; i < 64 * 64; i += 256) {
        int r = i >> 6, c = i & 63;
        tile[r][c] = V[(size_t)(t0 + r) * DM + h * HD + d0 + c];
    }
    __syncthreads();
    for (int i = tid; i < 64 * 64; i += 256) {
        int r = i >> 6, c = i & 63;
        Vt[(size_t)h * HD * SEQ + (size_t)(d0 + r) * SEQ + t0 + c] = tile[c][r];
    }
}

// ---------------------------------------------------------------------------
// concat 3 bias vectors [DM] into one [3*DM]
// ---------------------------------------------------------------------------
__global__ void concat3(const float* __restrict__ a, const float* __restrict__ b,
                        const float* __restrict__ c, float* __restrict__ o)
{
    int i = blockIdx.x * blockDim.x + threadIdx.x;
    if (i < DM) { o[i] = a[i]; o[DM + i] = b[i]; o[2 * DM + i] = c[i]; }
}

extern "C" void kernel_launch(void* const* d_in, const int* in_sizes, int n_in,
                              void* d_out, int out_size, void* d_ws, size_t ws_size,
                              hipStream_t stream)
{
    const float* x   = (const float*)d_in[0];
    const float* g1  = (const float*)d_in[1];
    const float* be1 = (const float*)d_in[2];
    const float* wq  = (const float*)d_in[3];
    const float* bq  = (const float*)d_in[4];
    const float* wk  = (const float*)d_in[5];
    const float* bk  = (const float*)d_in[6];
    const float* wv  = (const float*)d_in[7];
    const float* bv  = (const float*)d_in[8];
    const float* wo  = (const float*)d_in[9];
    const float* bo  = (const float*)d_in[10];
    const float* g2  = (const float*)d_in[11];
    const float* be2 = (const float*)d_in[12];
    const float* w1  = (const float*)d_in[13];
    const float* b1  = (const float*)d_in[14];
    const float* w2  = (const float*)d_in[15];
    const float* b2  = (const float*)d_in[16];
    float* out = (float*)d_out;

    char* ws = (char*)d_ws;
    const size_t MB = 1ull << 20;
    ushort_t* WQ   = (ushort_t*)(ws + 0 * MB);    // 2MB (contiguous with WK,WV for z-batch)
    ushort_t* WK   = (ushort_t*)(ws + 2 * MB);    // 2MB
    ushort_t* WV   = (ushort_t*)(ws + 4 * MB);    // 2MB
    ushort_t* WO   = (ushort_t*)(ws + 6 * MB);    // 2MB
    ushort_t* W1   = (ushort_t*)(ws + 8 * MB);    // 8MB
    ushort_t* W2   = (ushort_t*)(ws + 16 * MB);   // 8MB
    ushort_t* H    = (ushort_t*)(ws + 24 * MB);   // 8MB  (LN1 out, later LN2 out)
    ushort_t* Q    = (ushort_t*)(ws + 32 * MB);   // 8MB  (Q,K,V contiguous for z-batch)
    ushort_t* Kb   = (ushort_t*)(ws + 40 * MB);   // 8MB
    ushort_t* V    = (ushort_t*)(ws + 48 * MB);   // 8MB
    ushort_t* Vt   = (ushort_t*)(ws + 56 * MB);   // 8MB
    ushort_t* SC   = (ushort_t*)(ws + 64 * MB);   // 64MB scores; reused as F1 (32MB)
    ushort_t* O    = (ushort_t*)(ws + 128 * MB);  // 8MB
    float*    X1   = (float*)(ws + 136 * MB);     // 16MB -> ends at 152MB
    float*    BQKV = (float*)(ws + 152 * MB);     // 12KB

    // --- weight casts to bf16 ---
    auto cast = [&](const float* s, ushort_t* d, int n) {
        int n4 = n / 4;
        cast_f32_bf16<<<(n4 + 255) / 256, 256, 0, stream>>>((const float4*)s, d, n4);
    };
    cast(wq, WQ, DM * DM);
    cast(wk, WK, DM * DM);
    cast(wv, WV, DM * DM);
    cast(wo, WO, DM * DM);
    cast(w1, W1, DFF * DM);
    cast(w2, W2, DM * DFF);
    concat3<<<4, 256, 0, stream>>>(bq, bk, bv, BQKV);

    // --- LN1 ---
    layernorm_kernel<<<SEQ, 256, 0, stream>>>(x, g1, be1, H);

    dim3 blk(256);

    // --- QKV (z-batched over 3 weights) ---
    gemm_nt<true, false, false, true><<<dim3(DM / 128, SEQ / 128, 3), blk, 0, stream>>>(
        H, DM, WQ, DM, Q, DM, BQKV, nullptr, 0, DM, 1.0f,
        0, (size_t)DM * DM, (size_t)SEQ * DM, (size_t)DM);

    // --- V transpose per head ---
    transpose_head<<<dim3(SEQ / 64, HD / 64, NH), blk, 0, stream>>>(V, Vt);

    // --- scores = Q K^T / sqrt(HD), z over heads, bf16 out ---
    const float scale = 0.044194173824159216f;  // 1/sqrt(512)
    gemm_nt<false, false, false, true><<<dim3(SEQ / 128, SEQ / 128, NH), blk, 0, stream>>>(
        Q, DM, Kb, DM, SC, SEQ, nullptr, nullptr, 0, HD, scale,
        (size_t)HD, (size_t)HD, (size_t)SEQ * SEQ, 0);

    // --- softmax rows in place ---
    softmax_kernel<<<NH * SEQ, 256, 0, stream>>>(SC);

    // --- O = P V (z over heads; Vt makes it NT) ---
    gemm_nt<false, false, false, true><<<dim3(HD / 128, SEQ / 128, NH), blk, 0, stream>>>(
        SC, SEQ, Vt, SEQ, O, DM, nullptr, nullptr, 0, SEQ, 1.0f,
        (size_t)SEQ * SEQ, (size_t)HD * SEQ, (size_t)HD, 0);

    // --- X1 = x + O wo^T + bo (fp32 out) ---
    gemm_nt<true, false, true, false><<<dim3(DM / 128, SEQ / 128, 1), blk, 0, stream>>>(
        O, DM, WO, DM, X1, DM, bo, x, DM, DM, 1.0f, 0, 0, 0, 0);

    // --- LN2 ---
    layernorm_kernel<<<SEQ, 256, 0, stream>>>(X1, g2, be2, H);

    // --- FFN1 + GELU (F1 reuses SC buffer) ---
    ushort_t* F1 = SC;
    gemm_nt<true, true, false, true><<<dim3(DFF / 128, SEQ / 128, 1), blk, 0, stream>>>(
        H, DM, W1, DM, F1, DFF, b1, nullptr, 0, DM, 1.0f, 0, 0, 0, 0);

    // --- FFN2 + residual -> out (fp32) ---
    gemm_nt<true, false, true, false><<<dim3(DM / 128, SEQ / 128, 1), blk, 0, stream>>>(
        F1, DFF, W2, DFF, out, DM, b2, X1, DM, DFF, 1.0f, 0, 0, 0, 0);
}

// Round 2
// 507.933 us; speedup vs baseline: 1.0828x; 1.0828x over previous
//
#include <hip/hip_runtime.h>
#include <math.h>

#define SEQ 4096
#define DM  1024
#define DFF 4096
#define NH  2
#define HD  512

typedef unsigned short ushort_t;
typedef short  s16x8 __attribute__((ext_vector_type(8)));
typedef float  f32x4 __attribute__((ext_vector_type(4)));
typedef unsigned short u16x8 __attribute__((ext_vector_type(8)));

__device__ __forceinline__ float bf2f(unsigned short u) {
    return __uint_as_float(((unsigned)u) << 16);
}
__device__ __forceinline__ unsigned short f2bf(float f) {
    unsigned u = __float_as_uint(f);
    unsigned r = (u + 0x7fffu + ((u >> 16) & 1u)) >> 16;
    return (unsigned short)r;
}

__device__ __forceinline__ void async_load16(void* lds, const void* g) {
    __builtin_amdgcn_global_load_lds(
        (const __attribute__((address_space(1))) void*)g,
        (__attribute__((address_space(3))) void*)lds, 16, 0, 0);
}

// ---------------------------------------------------------------------------
// NT GEMM: C[M,N] = alpha * A[M,K] * B[N,K]^T (+bias[n]) (gelu) (+res[m,n])
// 128x128 block tile, 256 threads (4 waves, each 64x64 = 4x4 of 16x16x32
// MFMA). BK=64, global_load_lds width-16.
//
// LDS bank-conflict fix: row stride is 64 elem = 128 B == 0 mod 32 banks, so
// un-swizzled b128 reads are ~8-way conflicted (R1: 1.26e7 conflicts/disp).
// Physical 16B-granule p of row r holds logical granule p^(r&7). Staging picks
// each lane's GLOBAL column as (lane&7)^(lane>>3) (global_load_lds pins the
// LDS slot to lane*16); fragment reads XOR with (lr&7) -> 32 banks, 2-way.
//
// SPLITS>1: blockIdx.z = zb*SPLITS + s; slice s covers K-range [s*K,(s+1)*K)
// (K param = per-split length); C slab per z (fp32 partials, reduced later).
// ---------------------------------------------------------------------------
template<bool HAS_BIAS, bool DO_GELU, bool HAS_RES, bool OUT_BF16, int SPLITS>
__global__ __launch_bounds__(256)
void gemm_nt(const ushort_t* __restrict__ A, int lda,
             const ushort_t* __restrict__ B, int ldb,
             void* __restrict__ Cv, int ldc,
             const float* __restrict__ bias,
             const float* __restrict__ res, int ldres,
             int K, float alpha,
             size_t strA, size_t strB, size_t strC, size_t strBias)
{
    __shared__ alignas(16) ushort_t sA[128 * 64];
    __shared__ alignas(16) ushort_t sB[128 * 64];

    const int z  = blockIdx.z;
    const int zb = z / SPLITS;
    const int ks = (z % SPLITS) * K;
    A += (size_t)zb * strA;
    B += (size_t)zb * strB;
    if (HAS_BIAS) bias += (size_t)zb * strBias;

    const int tid   = threadIdx.x;
    const int lane  = tid & 63;
    const int wave  = tid >> 6;
    const int waveM = wave >> 1, waveN = wave & 1;
    const int m0 = blockIdx.y * 128, n0 = blockIdx.x * 128;
    const int lr = lane & 15, quad = lane >> 4;

    f32x4 acc[4][4] = {};

    const ushort_t* Ag = A + (size_t)m0 * lda + ks;
    const ushort_t* Bg = B + (size_t)n0 * ldb + ks;

    const int ldRow = (lane >> 3);                       // 0..7
    const int ldCol = (((lane & 7) ^ (lane >> 3)) * 8);  // swizzled global col

    for (int k0 = 0; k0 < K; k0 += 64) {
#pragma unroll
        for (int i = 0; i < 4; ++i) {
            int r = wave * 32 + i * 8 + ldRow;
            async_load16(&sA[(wave * 32 + i * 8) * 64],
                         Ag + (size_t)r * lda + k0 + ldCol);
            async_load16(&sB[(wave * 32 + i * 8) * 64],
                         Bg + (size_t)r * ldb + k0 + ldCol);
        }
        __syncthreads();   // compiler drains vmcnt before s_barrier

#pragma unroll
        for (int kk = 0; kk < 64; kk += 32) {
            const int pg = ((((kk >> 3) + quad) ^ (lr & 7)) << 3);
            s16x8 af[4], bfr[4];
#pragma unroll
            for (int mi = 0; mi < 4; ++mi)
                af[mi] = *(const s16x8*)&sA[(waveM * 64 + mi * 16 + lr) * 64 + pg];
#pragma unroll
            for (int ni = 0; ni < 4; ++ni)
                bfr[ni] = *(const s16x8*)&sB[(waveN * 64 + ni * 16 + lr) * 64 + pg];
#pragma unroll
            for (int mi = 0; mi < 4; ++mi)
#pragma unroll
                for (int ni = 0; ni < 4; ++ni)
                    acc[mi][ni] = __builtin_amdgcn_mfma_f32_16x16x32_bf16(
                        af[mi], bfr[ni], acc[mi][ni], 0, 0, 0);
        }
        __syncthreads();   // WAR before restaging
    }

    // Epilogue. C/D layout: col = lane&15, row = quad*4 + reg (m89-verified).
#pragma unroll
    for (int mi = 0; mi < 4; ++mi) {
#pragma unroll
        for (int ni = 0; ni < 4; ++ni) {
            int row = m0 + waveM * 64 + mi * 16 + quad * 4;
            int col = n0 + waveN * 64 + ni * 16 + lr;
            float bval = HAS_BIAS ? bias[col] : 0.0f;
#pragma unroll
            for (int r = 0; r < 4; ++r) {
                float v = acc[mi][ni][r] * alpha + bval;
                if (DO_GELU) {
                    float xx = v;
                    float inner = 0.7978845608028654f * (xx + 0.044715f * xx * xx * xx);
                    v = 0.5f * xx * (1.0f + tanhf(inner));
                }
                if (HAS_RES) v += res[(size_t)(row + r) * ldres + col];
                if (OUT_BF16)
                    ((ushort_t*)Cv)[(size_t)z * strC + (size_t)(row + r) * ldc + col] = f2bf(v);
                else
                    ((float*)Cv)[(size_t)z * strC + (size_t)(row + r) * ldc + col] = v;
            }
        }
    }
}

// ---------------------------------------------------------------------------
// Split-K reduce: out[row, z*colStride+col] = epi(sum_s P[z*S+s][row][col])
// slab = M*N (one fp32 slice). Vectorized float4. Epilogue fuses bias/res.
// ---------------------------------------------------------------------------
template<int S, bool HAS_BIAS, bool HAS_RES, bool OUT_BF16>
__global__ __launch_bounds__(256)
void reduce_splitk(const float* __restrict__ P, size_t slab,
                   void* __restrict__ outv, int N, int ldout, int colStride,
                   const float* __restrict__ bias,
                   const float* __restrict__ res, int ldres)
{
    const int z = blockIdx.z;
    const float* Pz = P + (size_t)z * S * slab;
    size_t i = ((size_t)blockIdx.x * 256 + threadIdx.x) * 4;
    if (i >= slab) return;
    int row = (int)(i / (size_t)N);
    int col = (int)(i - (size_t)row * N);
    float4 a = *(const float4*)(Pz + i);
#pragma unroll
    for (int s = 1; s < S; ++s) {
        float4 b = *(const float4*)(Pz + (size_t)s * slab + i);
        a.x += b.x; a.y += b.y; a.z += b.z; a.w += b.w;
    }
    int oc = z * colStride + col;
    if (HAS_BIAS) {
        a.x += bias[oc]; a.y += bias[oc + 1]; a.z += bias[oc + 2]; a.w += bias[oc + 3];
    }
    if (HAS_RES) {
        float4 r4 = *(const float4*)(res + (size_t)row * ldres + oc);
        a.x += r4.x; a.y += r4.y; a.z += r4.z; a.w += r4.w;
    }
    if (OUT_BF16) {
        ushort_t* o = (ushort_t*)outv + (size_t)row * ldout + oc;
        o[0] = f2bf(a.x); o[1] = f2bf(a.y); o[2] = f2bf(a.z); o[3] = f2bf(a.w);
    } else {
        *(float4*)((float*)outv + (size_t)row * ldout + oc) = a;
    }
}

// ---------------------------------------------------------------------------
// LayerNorm: one block per row of 1024 fp32; out bf16.
// ---------------------------------------------------------------------------
__global__ __launch_bounds__(256)
void layernorm_kernel(const float* __restrict__ x, const float* __restrict__ g,
                      const float* __restrict__ b, ushort_t* __restrict__ out)
{
    int row = blockIdx.x;
    int tid = threadIdx.x;
    float4 v = ((const float4*)(x + (size_t)row * DM))[tid];
    float s1 = v.x + v.y + v.z + v.w;
    float s2 = v.x * v.x + v.y * v.y + v.z * v.z + v.w * v.w;
#pragma unroll
    for (int o = 32; o > 0; o >>= 1) {
        s1 += __shfl_down(s1, o);
        s2 += __shfl_down(s2, o);
    }
    __shared__ float r1[4], r2[4];
    if ((tid & 63) == 0) { r1[tid >> 6] = s1; r2[tid >> 6] = s2; }
    __syncthreads();
    s1 = r1[0] + r1[1] + r1[2] + r1[3];
    s2 = r2[0] + r2[1] + r2[2] + r2[3];
    float mu  = s1 * (1.0f / DM);
    float var = s2 * (1.0f / DM) - mu * mu;
    float rs  = rsqrtf(var + 1e-5f);
    float4 gg = ((const float4*)g)[tid];
    float4 bb = ((const float4*)b)[tid];
    ushort_t* o = out + (size_t)row * DM + tid * 4;
    o[0] = f2bf((v.x - mu) * rs * gg.x + bb.x);
    o[1] = f2bf((v.y - mu) * rs * gg.y + bb.y);
    o[2] = f2bf((v.z - mu) * rs * gg.z + bb.z);
    o[3] = f2bf((v.w - mu) * rs * gg.w + bb.w);
}

// ---------------------------------------------------------------------------
// Row softmax in-place on bf16 scores [rows x 4096]. One block per row.
// ---------------------------------------------------------------------------
__global__ __launch_bounds__(256)
void softmax_kernel(ushort_t* __restrict__ S)
{
    size_t row = blockIdx.x;
    ushort_t* p = S + row * (size_t)SEQ;
    int tid = threadIdx.x;
    u16x8 ra = *(const u16x8*)(p + tid * 8);
    u16x8 rb = *(const u16x8*)(p + 2048 + tid * 8);
    float v[16];
    float vmax = -1e30f;
#pragma unroll
    for (int i = 0; i < 8; ++i) {
        v[i]     = bf2f(ra[i]);
        v[8 + i] = bf2f(rb[i]);
    }
#pragma unroll
    for (int i = 0; i < 16; ++i) vmax = fmaxf(vmax, v[i]);
#pragma unroll
    for (int o = 32; o > 0; o >>= 1) vmax = fmaxf(vmax, __shfl_down(vmax, o));
    __shared__ float sred[8];
    if ((tid & 63) == 0) sred[tid >> 6] = vmax;
    __syncthreads();
    vmax = fmaxf(fmaxf(sred[0], sred[1]), fmaxf(sred[2], sred[3]));
    float s = 0.0f;
#pragma unroll
    for (int i = 0; i < 16; ++i) { v[i] = __expf(v[i] - vmax); s += v[i]; }
#pragma unroll
    for (int o = 32; o > 0; o >>= 1) s += __shfl_down(s, o);
    if ((tid & 63) == 0) sred[4 + (tid >> 6)] = s;
    __syncthreads();
    s = sred[4] + sred[5] + sred[6] + sred[7];
    float inv = 1.0f / s;
    u16x8 oa, ob;
#pragma unroll
    for (int i = 0; i < 8; ++i) {
        oa[i] = f2bf(v[i] * inv);
        ob[i] = f2bf(v[8 + i] * inv);
    }
    *(u16x8*)(p + tid * 8) = oa;
    *(u16x8*)(p + 2048 + tid * 8) = ob;
}

// ---------------------------------------------------------------------------
// fp32 -> bf16 cast (vectorized)
// ---------------------------------------------------------------------------
__global__ __launch_bounds__(256)
void cast_f32_bf16(const float4* __restrict__ src, ushort_t* __restrict__ dst, int n4)
{
    int i = blockIdx.x * blockDim.x + threadIdx.x;
    if (i < n4) {
        float4 f = src[i];
        ushort_t* d = dst + (size_t)i * 4;
        d[0] = f2bf(f.x); d[1] = f2bf(f.y); d[2] = f2bf(f.z); d[3] = f2bf(f.w);
    }
}

// ---------------------------------------------------------------------------
// Per-head transpose: Vt[h][d][t] = V[t][h*HD + d]  (bf16), 64x64 LDS tiles.
// ---------------------------------------------------------------------------
__global__ __launch_bounds__(256)
void transpose_head(const ushort_t* __restrict__ V, ushort_t* __restrict__ Vt)
{
    __shared__ ushort_t tile[64][65];
    int t0 = blockIdx.x * 64, d0 = blockIdx.y * 64, h = blockIdx.z;
    int tid = threadIdx.x;
    for (int i = tid; i < 64 * 64; i += 256) {
        int r = i >> 6, c = i & 63;
        tile[r][c] = V[(size_t)(t0 + r) * DM + h * HD + d0 + c];
    }
    __syncthreads();
    for (int i = tid; i < 64 * 64; i += 256) {
        int r = i >> 6, c = i & 63;
        Vt[(size_t)h * HD * SEQ + (size_t)(d0 + r) * SEQ + t0 + c] = tile[c][r];
    }
}

__global__ void concat3(const float* __restrict__ a, const float* __restrict__ b,
                        const float* __restrict__ c, float* __restrict__ o)
{
    int i = blockIdx.x * blockDim.x + threadIdx.x;
    if (i < DM) { o[i] = a[i]; o[DM + i] = b[i]; o[2 * DM + i] = c[i]; }
}

extern "C" void kernel_launch(void* const* d_in, const int* in_sizes, int n_in,
                              void* d_out, int out_size, void* d_ws, size_t ws_size,
                              hipStream_t stream)
{
    const float* x   = (const float*)d_in[0];
    const float* g1  = (const float*)d_in[1];
    const float* be1 = (const float*)d_in[2];
    const float* wq  = (const float*)d_in[3];
    const float* bq  = (const float*)d_in[4];
    const float* wk  = (const float*)d_in[5];
    const float* bk  = (const float*)d_in[6];
    const float* wv  = (const float*)d_in[7];
    const float* bv  = (const float*)d_in[8];
    const float* wo  = (const float*)d_in[9];
    const float* bo  = (const float*)d_in[10];
    const float* g2  = (const float*)d_in[11];
    const float* be2 = (const float*)d_in[12];
    const float* w1  = (const float*)d_in[13];
    const float* b1  = (const float*)d_in[14];
    const float* w2  = (const float*)d_in[15];
    const float* b2  = (const float*)d_in[16];
    float* out = (float*)d_out;

    char* ws = (char*)d_ws;
    const size_t MB = 1ull << 20;
    ushort_t* WQ   = (ushort_t*)(ws + 0 * MB);    // 2MB (WQ,WK,WV contiguous)
    ushort_t* WK   = (ushort_t*)(ws + 2 * MB);
    ushort_t* WV   = (ushort_t*)(ws + 4 * MB);
    ushort_t* WO   = (ushort_t*)(ws + 6 * MB);
    ushort_t* W1   = (ushort_t*)(ws + 8 * MB);    // 8MB
    ushort_t* W2   = (ushort_t*)(ws + 16 * MB);   // 8MB
    ushort_t* H    = (ushort_t*)(ws + 24 * MB);   // 8MB  (LN1 out, later LN2 out)
    ushort_t* Q    = (ushort_t*)(ws + 32 * MB);   // 8MB  (Q,K,V contiguous)
    ushort_t* Kb   = (ushort_t*)(ws + 40 * MB);
    ushort_t* V    = (ushort_t*)(ws + 48 * MB);
    ushort_t* Vt   = (ushort_t*)(ws + 56 * MB);   // 8MB
    ushort_t* SC   = (ushort_t*)(ws + 64 * MB);   // 64MB scores; reused as F1
    ushort_t* O    = (ushort_t*)(ws + 128 * MB);  // 8MB
    float*    X1   = (float*)(ws + 136 * MB);     // 16MB
    float*    P    = (float*)(ws + 152 * MB);     // 64MB split-K partials
    float*    BQKV = (float*)(ws + 216 * MB);     // 12KB  -> total ~216.1MB

    auto cast = [&](const float* s, ushort_t* d, int n) {
        int n4 = n / 4;
        cast_f32_bf16<<<(n4 + 255) / 256, 256, 0, stream>>>((const float4*)s, d, n4);
    };
    cast(wq, WQ, DM * DM);
    cast(wk, WK, DM * DM);
    cast(wv, WV, DM * DM);
    cast(wo, WO, DM * DM);
    cast(w1, W1, DFF * DM);
    cast(w2, W2, DM * DFF);
    concat3<<<4, 256, 0, stream>>>(bq, bk, bv, BQKV);

    layernorm_kernel<<<SEQ, 256, 0, stream>>>(x, g1, be1, H);

    dim3 blk(256);

    // --- QKV (z-batched over 3 weights), 768 blocks ---
    gemm_nt<true, false, false, true, 1><<<dim3(DM / 128, SEQ / 128, 3), blk, 0, stream>>>(
        H, DM, WQ, DM, Q, DM, BQKV, nullptr, 0, DM, 1.0f,
        0, (size_t)DM * DM, (size_t)SEQ * DM, (size_t)DM);

    transpose_head<<<dim3(SEQ / 64, HD / 64, NH), blk, 0, stream>>>(V, Vt);

    // --- scores = Q K^T / sqrt(HD), z over heads, 2048 blocks ---
    const float scale = 0.044194173824159216f;  // 1/sqrt(512)
    gemm_nt<false, false, false, true, 1><<<dim3(SEQ / 128, SEQ / 128, NH), blk, 0, stream>>>(
        Q, DM, Kb, DM, SC, SEQ, nullptr, nullptr, 0, HD, scale,
        (size_t)HD, (size_t)HD, (size_t)SEQ * SEQ, 0);

    softmax_kernel<<<NH * SEQ, 256, 0, stream>>>(SC);

    // --- O = P V, split-K S=4 -> 1024 blocks; partials then reduce ---
    gemm_nt<false, false, false, false, 4><<<dim3(HD / 128, SEQ / 128, NH * 4), blk, 0, stream>>>(
        SC, SEQ, Vt, SEQ, P, HD, nullptr, nullptr, 0, SEQ / 4, 1.0f,
        (size_t)SEQ * SEQ, (size_t)HD * SEQ, (size_t)SEQ * HD, 0);
    reduce_splitk<4, false, false, true><<<dim3((SEQ * HD / 4) / 256, 1, NH), blk, 0, stream>>>(
        P, (size_t)SEQ * HD, O, HD, DM, HD, nullptr, nullptr, 0);

    // --- X1 = x + O wo^T + bo, split-K S=2 -> 512 blocks ---
    gemm_nt<false, false, false, false, 2><<<dim3(DM / 128, SEQ / 128, 2), blk, 0, stream>>>(
        O, DM, WO, DM, P, DM, nullptr, nullptr, 0, DM / 2, 1.0f,
        0, 0, (size_t)SEQ * DM, 0);
    reduce_splitk<2, true, true, false><<<dim3((SEQ * DM / 4) / 256, 1, 1), blk, 0, stream>>>(
        P, (size_t)SEQ * DM, X1, DM, DM, 0, bo, x, DM);

    layernorm_kernel<<<SEQ, 256, 0, stream>>>(X1, g2, be2, H);

    // --- FFN1 + GELU (F1 reuses SC), 1024 blocks ---
    ushort_t* F1 = SC;
    gemm_nt<true, true, false, true, 1><<<dim3(DFF / 128, SEQ / 128, 1), blk, 0, stream>>>(
        H, DM, W1, DM, F1, DFF, b1, nullptr, 0, DM, 1.0f, 0, 0, 0, 0);

    // --- FFN2, split-K S=4 -> 1024 blocks; reduce fuses b2 + X1 residual ---
    gemm_nt<false, false, false, false, 4><<<dim3(DM / 128, SEQ / 128, 4), blk, 0, stream>>>(
        F1, DFF, W2, DFF, P, DM, nullptr, nullptr, 0, DFF / 4, 1.0f,
        0, 0, (size_t)SEQ * DM, 0);
    reduce_splitk<4, true, true, false><<<dim3((SEQ * DM / 4) / 256, 1, 1), blk, 0, stream>>>(
        P, (size_t)SEQ * DM, out, DM, DM, 0, b2, X1, DM);
}